// Round 5
// baseline (158.797 us; speedup 1.0000x reference)
//
#include <hip/hip_runtime.h>
#include <stdint.h>

typedef unsigned int u32;
typedef unsigned long long u64;
typedef float f32x4 __attribute__((ext_vector_type(4)));

#define FACTOR  6.26f
#define D       2048
#define TPB     256
#define WPB     4        // one row per wave
#define CAP     256      // per-side candidate list capacity (mean 137, sd 11)
#define TH      1.5f
#define TH_BITS 0x3FC00000u

// Seeds for the 32nd-largest tail value of 2048 N(0,1): concentrated at 2.15 +/- 0.07.
#define SEED_LO (((u64)0x3FE66666u) << 32)   // 1.80f
#define SEED_HI (((u64)0x402147AEu) << 32)   // 2.52f

__device__ __forceinline__ float wsum_f(float v) {
#pragma unroll
    for (int d = 1; d < 64; d <<= 1) v += __shfl_xor(v, d, 64);
    return v;
}
__device__ __forceinline__ u32 wsum_u(u32 v) {
#pragma unroll
    for (int d = 1; d < 64; d <<= 1) v += __shfl_xor(v, d, 64);
    return v;
}
__device__ __forceinline__ float valof(u64 k) { return __uint_as_float((u32)(k >> 32)); }

__device__ __forceinline__ int cnt4(u64 k0, u64 k1, u64 k2, u64 k3, u64 mid) {
    return __popcll(__ballot(k0 >= mid)) + __popcll(__ballot(k1 >= mid))
         + __popcll(__ballot(k2 >= mid)) + __popcll(__ballot(k3 >= mid));
}

// Exact cut: returns cut with |{k : k >= cut}| == 32 (keys distinct).
// Final cut's hi-32 is always a valid non-negative float bit pattern
// (>=32 real keys are >= cut, and all real keys have hi32 <= 0x7F800000).
__device__ __forceinline__ u64 find_cut(u64 k0, u64 k1, u64 k2, u64 k3) {
    u64 lo = ((u64)TH_BITS) << 32;        // count(>=lo) = tot >= 32
    u64 hi = 0xFFFFFFFF00000000ull;       // count(>=hi) = 0
    int c = cnt4(k0, k1, k2, k3, SEED_LO);
    if (c == 32) return SEED_LO;
    if (c > 32) {
        lo = SEED_LO;
        int c2 = cnt4(k0, k1, k2, k3, SEED_HI);
        if (c2 == 32) return SEED_HI;
        if (c2 > 32) lo = SEED_HI; else hi = SEED_HI;
    } else {
        hi = SEED_LO;
    }
    while (hi - lo > 1ull) {
        u64 mid = lo + ((hi - lo) >> 1);
        int cm = cnt4(k0, k1, k2, k3, mid);
        if (cm >= 32) { lo = mid; if (cm == 32) break; } else hi = mid;
    }
    return lo;
}

struct CutRes { u64 cut; float tmp; };

// Cold exact fallback (degenerate rows only): full-row key bisect with global
// re-reads. Exact for ANY input incl. <32 signed elements (zero-key ties break
// by smallest index, matching lax.top_k).
__device__ __attribute__((noinline))
CutRes slow_cut(const float4* __restrict__ xr, int lane, int neg, float sum) {
    u64 lo = 0ull, hi = ((u64)0x7F800001u) << 32;
    while (hi - lo > 1ull) {
        u64 mid = lo + ((hi - lo) >> 1);
        u32 cl = 0;
#pragma unroll 1
        for (int q = 0; q < 8; ++q) {
            float4 f = xr[q * 64 + lane];
            float vv[4] = {f.x, f.y, f.z, f.w};
#pragma unroll
            for (int c = 0; c < 4; ++c) {
                float v = neg ? -vv[c] : vv[c];
                float pv = v > 0.f ? v : 0.f;
                int idx = q * 256 + lane * 4 + c;
                u64 k = ((u64)__float_as_uint(pv) << 32) | (u64)(u32)(2047 - idx);
                cl += (k >= mid) ? 1u : 0u;
            }
        }
        u32 c = wsum_u(cl);
        if (c >= 32u) { lo = mid; if (c == 32u) break; } else hi = mid;
    }
    float ts = 0.f;
#pragma unroll 1
    for (int q = 0; q < 8; ++q) {
        float4 f = xr[q * 64 + lane];
        float vv[4] = {f.x, f.y, f.z, f.w};
#pragma unroll
        for (int c = 0; c < 4; ++c) {
            float v = neg ? -vv[c] : vv[c];
            float pv = v > 0.f ? v : 0.f;
            int idx = q * 256 + lane * 4 + c;
            u64 k = ((u64)__float_as_uint(pv) << 32) | (u64)(u32)(2047 - idx);
            if (k >= lo) ts += pv;
        }
    }
    ts = wsum_f(ts);
    CutRes r; r.cut = lo; r.tmp = FACTOR * (sum - ts);
    return r;
}

__global__ void __launch_bounds__(TPB, 8)
kcomp_kernel(const float* __restrict__ x, float* __restrict__ out) {
    __shared__ u64 s_list[WPB][2][CAP];   // 16 KiB/block, per-wave private

    const int t    = threadIdx.x;
    const int lane = t & 63;
    const int wave = t >> 6;
    const size_t rbase = (size_t)(blockIdx.x * WPB + wave) * D;

    const float4* xr   = reinterpret_cast<const float4*>(x + rbase);
    f32x4*        out4 = reinterpret_cast<f32x4*>(out + rbase);

    // ---- pass 1: per-lane sums + candidate counts
    float rv[32];
    float ps = 0.f, ns = 0.f;
    u32 cP = 0, cN = 0;
#pragma unroll
    for (int q = 0; q < 8; ++q) {
        float4 f = xr[q * 64 + lane];
        rv[q*4+0] = f.x; rv[q*4+1] = f.y; rv[q*4+2] = f.z; rv[q*4+3] = f.w;
#pragma unroll
        for (int c = 0; c < 4; ++c) {
            float v = rv[q*4+c];
            ps += v > 0.f ? v : 0.f;
            ns += v < 0.f ? -v : 0.f;
            cP += v > TH  ? 1u : 0u;
            cN += v < -TH ? 1u : 0u;
        }
    }

    // ---- packed prefix scan for compaction offsets
    u32 packed = cP | (cN << 16);
    u32 inc = packed;
#pragma unroll
    for (int d = 1; d < 64; d <<= 1) {
        u32 n = __shfl_up(inc, (unsigned)d, 64);
        if (lane >= d) inc += n;
    }
    u32 tot  = __shfl(inc, 63, 64);
    u32 exc  = inc - packed;
    u32 totP = tot & 0xffffu, totN = tot >> 16;
    u32 offP = exc & 0xffffu, offN = exc >> 16;
    float sumP = wsum_f(ps), sumN = wsum_f(ns);

    const bool fastP = (totP >= 32u && totP <= CAP);
    const bool fastN = (totN >= 32u && totN <= CAP);
    u64* listP = s_list[wave][0];
    u64* listN = s_list[wave][1];

    // ---- pass 2: compact u64 keys (value-bits || 2047-idx) to LDS
#pragma unroll
    for (int q = 0; q < 8; ++q) {
#pragma unroll
        for (int c = 0; c < 4; ++c) {
            float v = rv[q*4+c];
            u32 fi = (u32)(q * 256 + lane * 4 + c);
            if (fastP && v > TH)
                listP[offP++] = ((u64)__float_as_uint(v)  << 32) | (u64)(2047u - fi);
            if (fastN && v < -TH)
                listN[offN++] = ((u64)__float_as_uint(-v) << 32) | (u64)(2047u - fi);
        }
    }

    // ---- selection per side: cut + energy term
    u64 cutP, cutN;
    float PtmpP, NtmpN;
    if (fastP) {
        u64 p0 = (lane       < (int)totP) ? listP[lane]       : 0ull;
        u64 p1 = (lane + 64  < (int)totP) ? listP[lane + 64]  : 0ull;
        u64 p2 = (lane + 128 < (int)totP) ? listP[lane + 128] : 0ull;
        u64 p3 = (lane + 192 < (int)totP) ? listP[lane + 192] : 0ull;
        cutP = find_cut(p0, p1, p2, p3);
        float ts = (p0 >= cutP ? valof(p0) : 0.f) + (p1 >= cutP ? valof(p1) : 0.f)
                 + (p2 >= cutP ? valof(p2) : 0.f) + (p3 >= cutP ? valof(p3) : 0.f);
        ts = wsum_f(ts);
        PtmpP = FACTOR * (sumP - ts);
    } else {
        CutRes r = slow_cut(xr, lane, 0, sumP);
        cutP = r.cut; PtmpP = r.tmp;
    }
    if (fastN) {
        u64 n0 = (lane       < (int)totN) ? listN[lane]       : 0ull;
        u64 n1 = (lane + 64  < (int)totN) ? listN[lane + 64]  : 0ull;
        u64 n2 = (lane + 128 < (int)totN) ? listN[lane + 128] : 0ull;
        u64 n3 = (lane + 192 < (int)totN) ? listN[lane + 192] : 0ull;
        cutN = find_cut(n0, n1, n2, n3);
        float ts = (n0 >= cutN ? valof(n0) : 0.f) + (n1 >= cutN ? valof(n1) : 0.f)
                 + (n2 >= cutN ? valof(n2) : 0.f) + (n3 >= cutN ? valof(n3) : 0.f);
        ts = wsum_f(ts);
        NtmpN = FACTOR * (sumN - ts);
    } else {
        CutRes r = slow_cut(xr, lane, 1, sumN);
        cutN = r.cut; NtmpN = r.tmp;
    }

    // ---- pass 3: membership test + single coalesced nontemporal store.
    // winner(elem) <=> key >= cut, decomposed lexicographically:
    //   (pv > cut_val) || (pv == cut_val && (2047-idx) >= cut_lo32)
    const float cPf = __uint_as_float((u32)(cutP >> 32));
    const u32   cPi = (u32)cutP;
    const float cNf = __uint_as_float((u32)(cutN >> 32));
    const u32   cNi = (u32)cutN;

#pragma unroll
    for (int q = 0; q < 8; ++q) {
        float o[4];
#pragma unroll
        for (int c = 0; c < 4; ++c) {
            float v = rv[q*4+c];
            u32 ip = 2047u - (u32)(q * 256 + lane * 4 + c);
            float pv = v > 0.f ? v : 0.f;
            float nv = v < 0.f ? -v : 0.f;
            bool wP = (pv > cPf) || (pv == cPf && ip >= cPi);
            bool wN = (nv > cNf) || (nv == cNf && ip >= cNi);
            float val = wP ? (pv + PtmpP) : 0.f;
            if (wN) val -= (nv + NtmpN);
            o[c] = val;
        }
        f32x4 ov = {o[0], o[1], o[2], o[3]};
        __builtin_nontemporal_store(ov, &out4[q * 64 + lane]);
    }
}

extern "C" void kernel_launch(void* const* d_in, const int* in_sizes, int n_in,
                              void* d_out, int out_size, void* d_ws, size_t ws_size,
                              hipStream_t stream) {
    const float* x = (const float*)d_in[0];
    float* out = (float*)d_out;
    const int rows = in_sizes[0] / D;          // 16384
    kcomp_kernel<<<rows / WPB, TPB, 0, stream>>>(x, out);
}

// Round 6
// 80.259 us; speedup vs baseline: 1.9786x; 1.9786x over previous
//
#include <hip/hip_runtime.h>
#include <stdint.h>

typedef unsigned int u32;
typedef unsigned long long u64;

#define FACTOR  6.26f
#define D       2048
#define TPB     256
#define WPB     4        // one row per wave
#define CAP     256      // per-side candidate list capacity (mean 137, sd 11)
#define TH      1.5f
#define TH_BITS 0x3FC00000u

// Seeds for the 32nd-largest tail value of 2048 N(0,1): concentrated at 2.15 +/- 0.07.
#define SEED_LO (((u64)0x3FE66666u) << 32)   // 1.80f
#define SEED_HI (((u64)0x402147AEu) << 32)   // 2.52f

__device__ __forceinline__ float wsum_f(float v) {
#pragma unroll
    for (int d = 1; d < 64; d <<= 1) v += __shfl_xor(v, d, 64);
    return v;
}
__device__ __forceinline__ u32 wsum_u(u32 v) {
#pragma unroll
    for (int d = 1; d < 64; d <<= 1) v += __shfl_xor(v, d, 64);
    return v;
}
__device__ __forceinline__ float valof(u64 k) { return __uint_as_float((u32)(k >> 32)); }

__device__ __forceinline__ int cnt4(u64 k0, u64 k1, u64 k2, u64 k3, u64 mid) {
    return __popcll(__ballot(k0 >= mid)) + __popcll(__ballot(k1 >= mid))
         + __popcll(__ballot(k2 >= mid)) + __popcll(__ballot(k3 >= mid));
}

// Exact cut: returns cut with |{k : k >= cut}| == 32 (keys distinct).
// Final cut's hi-32 is always a valid non-negative float bit pattern
// (>=32 real keys are >= cut, and all real keys have hi32 <= 0x7F800000).
__device__ __forceinline__ u64 find_cut(u64 k0, u64 k1, u64 k2, u64 k3) {
    u64 lo = ((u64)TH_BITS) << 32;        // count(>=lo) = tot >= 32
    u64 hi = 0xFFFFFFFF00000000ull;       // count(>=hi) = 0
    int c = cnt4(k0, k1, k2, k3, SEED_LO);
    if (c == 32) return SEED_LO;
    if (c > 32) {
        lo = SEED_LO;
        int c2 = cnt4(k0, k1, k2, k3, SEED_HI);
        if (c2 == 32) return SEED_HI;
        if (c2 > 32) lo = SEED_HI; else hi = SEED_HI;
    } else {
        hi = SEED_LO;
    }
    while (hi - lo > 1ull) {
        u64 mid = lo + ((hi - lo) >> 1);
        int cm = cnt4(k0, k1, k2, k3, mid);
        if (cm >= 32) { lo = mid; if (cm == 32) break; } else hi = mid;
    }
    return lo;
}

struct CutRes { u64 cut; float tmp; };

// Cold exact fallback (degenerate rows only): full-row key bisect with global
// re-reads. Exact for ANY input incl. <32 signed elements (zero-key ties break
// by smallest index, matching lax.top_k).
__device__ __attribute__((noinline))
CutRes slow_cut(const float4* __restrict__ xr, int lane, int neg, float sum) {
    u64 lo = 0ull, hi = ((u64)0x7F800001u) << 32;
    while (hi - lo > 1ull) {
        u64 mid = lo + ((hi - lo) >> 1);
        u32 cl = 0;
#pragma unroll 1
        for (int q = 0; q < 8; ++q) {
            float4 f = xr[q * 64 + lane];
            float vv[4] = {f.x, f.y, f.z, f.w};
#pragma unroll
            for (int c = 0; c < 4; ++c) {
                float v = neg ? -vv[c] : vv[c];
                float pv = v > 0.f ? v : 0.f;
                int idx = q * 256 + lane * 4 + c;
                u64 k = ((u64)__float_as_uint(pv) << 32) | (u64)(u32)(2047 - idx);
                cl += (k >= mid) ? 1u : 0u;
            }
        }
        u32 c = wsum_u(cl);
        if (c >= 32u) { lo = mid; if (c == 32u) break; } else hi = mid;
    }
    float ts = 0.f;
#pragma unroll 1
    for (int q = 0; q < 8; ++q) {
        float4 f = xr[q * 64 + lane];
        float vv[4] = {f.x, f.y, f.z, f.w};
#pragma unroll
        for (int c = 0; c < 4; ++c) {
            float v = neg ? -vv[c] : vv[c];
            float pv = v > 0.f ? v : 0.f;
            int idx = q * 256 + lane * 4 + c;
            u64 k = ((u64)__float_as_uint(pv) << 32) | (u64)(u32)(2047 - idx);
            if (k >= lo) ts += pv;
        }
    }
    ts = wsum_f(ts);
    CutRes r; r.cut = lo; r.tmp = FACTOR * (sum - ts);
    return r;
}

__global__ void __launch_bounds__(TPB, 4)
kcomp_kernel(const float* __restrict__ x, float* __restrict__ out) {
    __shared__ u64 s_list[WPB][2][CAP];   // 16 KiB/block, per-wave private

    const int t    = threadIdx.x;
    const int lane = t & 63;
    const int wave = t >> 6;
    const size_t rbase = (size_t)(blockIdx.x * WPB + wave) * D;

    const float4* xr   = reinterpret_cast<const float4*>(x + rbase);
    float4*       out4 = reinterpret_cast<float4*>(out + rbase);

    // ---- pass 1: load row to regs, per-lane sums + candidate counts
    float rv[32];
    float ps = 0.f, ns = 0.f;
    u32 cP = 0, cN = 0;
#pragma unroll
    for (int q = 0; q < 8; ++q) {
        float4 f = xr[q * 64 + lane];
        rv[q*4+0] = f.x; rv[q*4+1] = f.y; rv[q*4+2] = f.z; rv[q*4+3] = f.w;
#pragma unroll
        for (int c = 0; c < 4; ++c) {
            float v = rv[q*4+c];
            ps += v > 0.f ? v : 0.f;
            ns += v < 0.f ? -v : 0.f;
            cP += v > TH  ? 1u : 0u;
            cN += v < -TH ? 1u : 0u;
        }
    }

    // ---- packed prefix scan for compaction offsets
    u32 packed = cP | (cN << 16);
    u32 inc = packed;
#pragma unroll
    for (int d = 1; d < 64; d <<= 1) {
        u32 n = __shfl_up(inc, (unsigned)d, 64);
        if (lane >= d) inc += n;
    }
    u32 tot  = __shfl(inc, 63, 64);
    u32 exc  = inc - packed;
    u32 totP = tot & 0xffffu, totN = tot >> 16;
    u32 offP = exc & 0xffffu, offN = exc >> 16;
    float sumP = wsum_f(ps), sumN = wsum_f(ns);

    const bool fastP = (totP >= 32u && totP <= CAP);
    const bool fastN = (totN >= 32u && totN <= CAP);
    u64* listP = s_list[wave][0];
    u64* listN = s_list[wave][1];

    // ---- pass 2: compact u64 keys (value-bits || 2047-idx) to LDS
#pragma unroll
    for (int q = 0; q < 8; ++q) {
#pragma unroll
        for (int c = 0; c < 4; ++c) {
            float v = rv[q*4+c];
            u32 fi = (u32)(q * 256 + lane * 4 + c);
            if (fastP && v > TH)
                listP[offP++] = ((u64)__float_as_uint(v)  << 32) | (u64)(2047u - fi);
            if (fastN && v < -TH)
                listN[offN++] = ((u64)__float_as_uint(-v) << 32) | (u64)(2047u - fi);
        }
    }

    // ---- selection per side: cut + energy term
    u64 cutP, cutN;
    float PtmpP, NtmpN;
    if (fastP) {
        u64 p0 = (lane       < (int)totP) ? listP[lane]       : 0ull;
        u64 p1 = (lane + 64  < (int)totP) ? listP[lane + 64]  : 0ull;
        u64 p2 = (lane + 128 < (int)totP) ? listP[lane + 128] : 0ull;
        u64 p3 = (lane + 192 < (int)totP) ? listP[lane + 192] : 0ull;
        cutP = find_cut(p0, p1, p2, p3);
        float ts = (p0 >= cutP ? valof(p0) : 0.f) + (p1 >= cutP ? valof(p1) : 0.f)
                 + (p2 >= cutP ? valof(p2) : 0.f) + (p3 >= cutP ? valof(p3) : 0.f);
        ts = wsum_f(ts);
        PtmpP = FACTOR * (sumP - ts);
    } else {
        CutRes r = slow_cut(xr, lane, 0, sumP);
        cutP = r.cut; PtmpP = r.tmp;
    }
    if (fastN) {
        u64 n0 = (lane       < (int)totN) ? listN[lane]       : 0ull;
        u64 n1 = (lane + 64  < (int)totN) ? listN[lane + 64]  : 0ull;
        u64 n2 = (lane + 128 < (int)totN) ? listN[lane + 128] : 0ull;
        u64 n3 = (lane + 192 < (int)totN) ? listN[lane + 192] : 0ull;
        cutN = find_cut(n0, n1, n2, n3);
        float ts = (n0 >= cutN ? valof(n0) : 0.f) + (n1 >= cutN ? valof(n1) : 0.f)
                 + (n2 >= cutN ? valof(n2) : 0.f) + (n3 >= cutN ? valof(n3) : 0.f);
        ts = wsum_f(ts);
        NtmpN = FACTOR * (sumN - ts);
    } else {
        CutRes r = slow_cut(xr, lane, 1, sumN);
        cutN = r.cut; NtmpN = r.tmp;
    }

    // ---- pass 3: membership test + single coalesced store (row from regs).
    // winner(elem) <=> key >= cut, decomposed lexicographically:
    //   (pv > cut_val) || (pv == cut_val && (2047-idx) >= cut_lo32)
    const float cPf = __uint_as_float((u32)(cutP >> 32));
    const u32   cPi = (u32)cutP;
    const float cNf = __uint_as_float((u32)(cutN >> 32));
    const u32   cNi = (u32)cutN;

#pragma unroll
    for (int q = 0; q < 8; ++q) {
        float o[4];
#pragma unroll
        for (int c = 0; c < 4; ++c) {
            float v = rv[q*4+c];
            u32 ip = 2047u - (u32)(q * 256 + lane * 4 + c);
            float pv = v > 0.f ? v : 0.f;
            float nv = v < 0.f ? -v : 0.f;
            bool wP = (pv > cPf) || (pv == cPf && ip >= cPi);
            bool wN = (nv > cNf) || (nv == cNf && ip >= cNi);
            float val = wP ? (pv + PtmpP) : 0.f;
            if (wN) val -= (nv + NtmpN);
            o[c] = val;
        }
        out4[q * 64 + lane] = make_float4(o[0], o[1], o[2], o[3]);
    }
}

extern "C" void kernel_launch(void* const* d_in, const int* in_sizes, int n_in,
                              void* d_out, int out_size, void* d_ws, size_t ws_size,
                              hipStream_t stream) {
    const float* x = (const float*)d_in[0];
    float* out = (float*)d_out;
    const int rows = in_sizes[0] / D;          // 16384
    kcomp_kernel<<<rows / WPB, TPB, 0, stream>>>(x, out);
}

// Round 7
// 52.828 us; speedup vs baseline: 3.0059x; 1.5193x over previous
//
#include <hip/hip_runtime.h>
#include <stdint.h>

typedef unsigned int u32;
typedef unsigned long long u64;

#define FACTOR  6.26f
#define D       2048
#define TPB     256
#define WPB     4        // one row per wave
#define CAP     256      // per-side candidate list capacity (mean 137, sd 11.3)
#define TH      1.5f
#define TH_BITS 0x3FC00000u

// Seeds for the 32nd-largest tail value of 2048 N(0,1): concentrated at 2.15 +/- 0.07.
#define SEED_LO (((u64)0x3FE66666u) << 32)   // 1.80f
#define SEED_HI (((u64)0x402147AEu) << 32)   // 2.52f

__device__ __forceinline__ float wsum_f(float v) {
#pragma unroll
    for (int d = 1; d < 64; d <<= 1) v += __shfl_xor(v, d, 64);
    return v;
}
__device__ __forceinline__ u32 wsum_u(u32 v) {
#pragma unroll
    for (int d = 1; d < 64; d <<= 1) v += __shfl_xor(v, d, 64);
    return v;
}
__device__ __forceinline__ float valof(u64 k) { return __uint_as_float((u32)(k >> 32)); }

__device__ __forceinline__ int cnt4(u64 k0, u64 k1, u64 k2, u64 k3, u64 mid) {
    return __popcll(__ballot(k0 >= mid)) + __popcll(__ballot(k1 >= mid))
         + __popcll(__ballot(k2 >= mid)) + __popcll(__ballot(k3 >= mid));
}

// Exact cut: returns cut with |{k : k >= cut}| == 32 (keys distinct, nonzero
// real keys all > TH_BITS<<32, empty slots 0). Seeded bisect, exact always.
__device__ __forceinline__ u64 find_cut(u64 k0, u64 k1, u64 k2, u64 k3) {
    u64 lo = ((u64)TH_BITS) << 32;        // count(>=lo) = tot >= 32
    u64 hi = 0xFFFFFFFF00000000ull;       // count(>=hi) = 0
    int c = cnt4(k0, k1, k2, k3, SEED_LO);
    if (c == 32) return SEED_LO;
    if (c > 32) {
        lo = SEED_LO;
        int c2 = cnt4(k0, k1, k2, k3, SEED_HI);
        if (c2 == 32) return SEED_HI;
        if (c2 > 32) lo = SEED_HI; else hi = SEED_HI;
    } else {
        hi = SEED_LO;
    }
    while (hi - lo > 1ull) {
        u64 mid = lo + ((hi - lo) >> 1);
        int cm = cnt4(k0, k1, k2, k3, mid);
        if (cm >= 32) { lo = mid; if (cm == 32) break; } else hi = mid;
    }
    return lo;  // distinct keys => |{k >= lo}| == 32 at both exits
}

// Cold exact fallback (prob ~1e-19/row for this data): full-row key bisect with
// global re-reads + atomicAdd scatter (handles P/N overlap possible only here).
// Called AFTER zeros are stored and drained.
__device__ __attribute__((noinline))
void slow_side(const float4* __restrict__ xr, float* __restrict__ outrow,
               int lane, int neg, float sum) {
    u64 lo = 0ull, hi = ((u64)0x7F800001u) << 32;
    while (hi - lo > 1ull) {
        u64 mid = lo + ((hi - lo) >> 1);
        u32 cl = 0;
#pragma unroll 1
        for (int q = 0; q < 8; ++q) {
            float4 f = xr[q * 64 + lane];
            float vv[4] = {f.x, f.y, f.z, f.w};
#pragma unroll
            for (int c = 0; c < 4; ++c) {
                float v = neg ? -vv[c] : vv[c];
                float pv = v > 0.f ? v : 0.f;
                int idx = q * 256 + lane * 4 + c;
                u64 k = ((u64)__float_as_uint(pv) << 32) | (u64)(u32)(2047 - idx);
                cl += (k >= mid) ? 1u : 0u;
            }
        }
        u32 c = wsum_u(cl);
        if (c >= 32u) { lo = mid; if (c == 32u) break; } else hi = mid;
    }
    float ts = 0.f;
#pragma unroll 1
    for (int q = 0; q < 8; ++q) {
        float4 f = xr[q * 64 + lane];
        float vv[4] = {f.x, f.y, f.z, f.w};
#pragma unroll
        for (int c = 0; c < 4; ++c) {
            float v = neg ? -vv[c] : vv[c];
            float pv = v > 0.f ? v : 0.f;
            int idx = q * 256 + lane * 4 + c;
            u64 k = ((u64)__float_as_uint(pv) << 32) | (u64)(u32)(2047 - idx);
            if (k >= lo) ts += pv;
        }
    }
    ts = wsum_f(ts);
    float tmp = FACTOR * (sum - ts);
    float sgn = neg ? -1.f : 1.f;
#pragma unroll 1
    for (int q = 0; q < 8; ++q) {
        float4 f = xr[q * 64 + lane];
        float vv[4] = {f.x, f.y, f.z, f.w};
#pragma unroll
        for (int c = 0; c < 4; ++c) {
            float v = neg ? -vv[c] : vv[c];
            float pv = v > 0.f ? v : 0.f;
            int idx = q * 256 + lane * 4 + c;
            u64 k = ((u64)__float_as_uint(pv) << 32) | (u64)(u32)(2047 - idx);
            if (k >= lo) atomicAdd(&outrow[idx], sgn * (pv + tmp));
        }
    }
}

__global__ void __launch_bounds__(TPB, 8)
kcomp_kernel(const float* __restrict__ x, float* __restrict__ out) {
    __shared__ u64 s_list[WPB][2][CAP];   // 16 KiB/block, per-wave private

    const int t    = threadIdx.x;
    const int lane = t & 63;
    const int wave = t >> 6;
    const size_t rbase = (size_t)(blockIdx.x * WPB + wave) * D;

    const float4* xr     = reinterpret_cast<const float4*>(x + rbase);
    float4*       out4   = reinterpret_cast<float4*>(out + rbase);
    float*        outrow = out + rbase;

    // ---- pass 1: load row to regs, per-lane sums + candidate counts
    float rv[32];
    float ps = 0.f, ns = 0.f;
    u32 cP = 0, cN = 0;
#pragma unroll
    for (int q = 0; q < 8; ++q) {
        float4 f = xr[q * 64 + lane];
        rv[q*4+0] = f.x; rv[q*4+1] = f.y; rv[q*4+2] = f.z; rv[q*4+3] = f.w;
#pragma unroll
        for (int c = 0; c < 4; ++c) {
            float v = rv[q*4+c];
            ps += v > 0.f ? v : 0.f;
            ns += v < 0.f ? -v : 0.f;
            cP += v > TH  ? 1u : 0u;
            cN += v < -TH ? 1u : 0u;
        }
    }

    // ---- packed prefix scan for compaction offsets
    u32 packed = cP | (cN << 16);
    u32 inc = packed;
#pragma unroll
    for (int d = 1; d < 64; d <<= 1) {
        u32 n = __shfl_up(inc, (unsigned)d, 64);
        if (lane >= d) inc += n;
    }
    u32 tot  = __shfl(inc, 63, 64);
    u32 exc  = inc - packed;
    u32 totP = tot & 0xffffu, totN = tot >> 16;
    u32 offP = exc & 0xffffu, offN = exc >> 16;
    float sumP = wsum_f(ps), sumN = wsum_f(ns);

    const bool fastP = (totP >= 32u && totP <= CAP);
    const bool fastN = (totN >= 32u && totN <= CAP);
    u64* listP = s_list[wave][0];
    u64* listN = s_list[wave][1];

    // ---- pass 2: compact u64 keys (value-bits || 2047-idx) to LDS; rv dies here
#pragma unroll
    for (int q = 0; q < 8; ++q) {
#pragma unroll
        for (int c = 0; c < 4; ++c) {
            float v = rv[q*4+c];
            u32 fi = (u32)(q * 256 + lane * 4 + c);
            if (fastP && v > TH)
                listP[offP++] = ((u64)__float_as_uint(v)  << 32) | (u64)(2047u - fi);
            if (fastN && v < -TH)
                listN[offN++] = ((u64)__float_as_uint(-v) << 32) | (u64)(2047u - fi);
        }
    }

    // ---- selection per side (lists in 4 u64 regs/lane); slow rows deferred
    u64 cutP = 0, cutN = 0;
    float PtmpP = 0.f, NtmpN = 0.f;
    u64 p0 = 0, p1 = 0, p2 = 0, p3 = 0, n0 = 0, n1 = 0, n2 = 0, n3 = 0;
    if (fastP) {
        p0 = (lane       < (int)totP) ? listP[lane]       : 0ull;
        p1 = (lane + 64  < (int)totP) ? listP[lane + 64]  : 0ull;
        p2 = (lane + 128 < (int)totP) ? listP[lane + 128] : 0ull;
        p3 = (lane + 192 < (int)totP) ? listP[lane + 192] : 0ull;
        cutP = find_cut(p0, p1, p2, p3);
        float ts = (p0 >= cutP ? valof(p0) : 0.f) + (p1 >= cutP ? valof(p1) : 0.f)
                 + (p2 >= cutP ? valof(p2) : 0.f) + (p3 >= cutP ? valof(p3) : 0.f);
        ts = wsum_f(ts);
        PtmpP = FACTOR * (sumP - ts);
    }
    if (fastN) {
        n0 = (lane       < (int)totN) ? listN[lane]       : 0ull;
        n1 = (lane + 64  < (int)totN) ? listN[lane + 64]  : 0ull;
        n2 = (lane + 128 < (int)totN) ? listN[lane + 128] : 0ull;
        n3 = (lane + 192 < (int)totN) ? listN[lane + 192] : 0ull;
        cutN = find_cut(n0, n1, n2, n3);
        float ts = (n0 >= cutN ? valof(n0) : 0.f) + (n1 >= cutN ? valof(n1) : 0.f)
                 + (n2 >= cutN ? valof(n2) : 0.f) + (n3 >= cutN ? valof(n3) : 0.f);
        ts = wsum_f(ts);
        NtmpN = FACTOR * (sumN - ts);
    }

    // ---- zeros + scatter back-to-back: lines stay L2-resident between the
    // zero store and the winner store -> single write-back, no RMW.
#pragma unroll
    for (int q = 0; q < 8; ++q)
        out4[q * 64 + lane] = make_float4(0.f, 0.f, 0.f, 0.f);

    asm volatile("s_waitcnt vmcnt(0)" ::: "memory");

    const bool anyslow = !(fastP && fastN);
    if (fastP) {
#pragma unroll
        for (int s = 0; s < 4; ++s) {
            u64 k = (s == 0) ? p0 : (s == 1) ? p1 : (s == 2) ? p2 : p3;
            if (k >= cutP) {
                int idx = 2047 - (int)(k & 0x7FFull);
                float val = valof(k) + PtmpP;
                if (anyslow) atomicAdd(&outrow[idx], val);
                else         outrow[idx] = val;
            }
        }
    }
    if (fastN) {
#pragma unroll
        for (int s = 0; s < 4; ++s) {
            u64 k = (s == 0) ? n0 : (s == 1) ? n1 : (s == 2) ? n2 : n3;
            if (k >= cutN) {
                int idx = 2047 - (int)(k & 0x7FFull);
                float val = -(valof(k) + NtmpN);
                if (anyslow) atomicAdd(&outrow[idx], val);
                else         outrow[idx] = val;
            }
        }
    }
    if (!fastP) slow_side(xr, outrow, lane, 0, sumP);
    if (!fastN) slow_side(xr, outrow, lane, 1, sumN);
}

extern "C" void kernel_launch(void* const* d_in, const int* in_sizes, int n_in,
                              void* d_out, int out_size, void* d_ws, size_t ws_size,
                              hipStream_t stream) {
    const float* x = (const float*)d_in[0];
    float* out = (float*)d_out;
    const int rows = in_sizes[0] / D;          // 16384
    kcomp_kernel<<<rows / WPB, TPB, 0, stream>>>(x, out);
}